// Round 19
// baseline (383.245 us; speedup 1.0000x reference)
//
#include <hip/hip_runtime.h>
#include <hip/hip_bf16.h>

// ---------- types & helpers ----------
typedef __attribute__((ext_vector_type(8))) short short8;   // 8 bf16 (4 VGPRs)
typedef __attribute__((ext_vector_type(4))) float f32x4;

#define AS1 __attribute__((address_space(1)))
#define AS3 __attribute__((address_space(3)))

__device__ __forceinline__ void gload16(const void* g, void* l) {
  __builtin_amdgcn_global_load_lds((const AS1 unsigned int*)g,
                                   (AS3 unsigned int*)l, 16, 0, 0);
}

__device__ __forceinline__ unsigned short f2bf(float x) {
  unsigned u = __float_as_uint(x);
  u = (u + 0x7FFFu + ((u >> 16) & 1u)) >> 16;  // RNE
  return (unsigned short)u;
}

__device__ __forceinline__ short8 lds8(const unsigned short* p) {
  return *(const short8*)p;
}

// Swizzled 16B LDS read: logical (row, byteInRow) of a 128B-row tile.
// Swizzle: 16B-slot ^= row&7.
__device__ __forceinline__ short8 lds8s(const unsigned short* base, int row, int byteInRow) {
  const int a = (row << 7) + (byteInRow ^ ((row & 7) << 4));
  return *(const short8*)((const char*)base + a);
}

// Problem constants: L=S=2048, N=4, E=1024, H=16, D=64; rows = L*N = 8192
#define LL 2048
#define NB 4
#define EE 1024
#define HH 16
#define DD 64
#define MROWS 8192
#define SC2 0.18033688f  // 0.125 * log2(e): softmax in exp2 domain
#define MFIX 16.0f       // fixed exponent shift (max sc*SC2 ~ 6 sigma ~ 9 << 16)

// ---------- batched token conv: query/key/value in ONE dispatch ----------
__global__ __launch_bounds__(256) void conv_tok3(const float* __restrict__ s0,
                                                 const float* __restrict__ s1,
                                                 const float* __restrict__ s2,
                                                 unsigned short* __restrict__ d0,
                                                 unsigned short* __restrict__ d1,
                                                 unsigned short* __restrict__ d2) {
  const float* src;
  unsigned short* dst;
  switch (blockIdx.y) {
    case 0: src = s0; dst = d0; break;
    case 1: src = s1; dst = d1; break;
    default: src = s2; dst = d2; break;
  }
  int i = blockIdx.x * 256 + threadIdx.x;
  float4 v = ((const float4*)src)[i];
  ushort4 o;
  o.x = f2bf(v.x); o.y = f2bf(v.y); o.z = f2bf(v.z); o.w = f2bf(v.w);
  ((ushort4*)dst)[i] = o;
}

// ---------- batched 4-weight conv ----------
__global__ __launch_bounds__(256) void conv_w4(const float* __restrict__ s0,
                                               const float* __restrict__ s1,
                                               const float* __restrict__ s2,
                                               const float* __restrict__ s3,
                                               unsigned short* __restrict__ d0,
                                               unsigned short* __restrict__ d1,
                                               unsigned short* __restrict__ d2,
                                               unsigned short* __restrict__ d3) {
  const float* src;
  unsigned short* dst;
  switch (blockIdx.y) {
    case 0: src = s0; dst = d0; break;
    case 1: src = s1; dst = d1; break;
    case 2: src = s2; dst = d2; break;
    default: src = s3; dst = d3; break;
  }
  int i = blockIdx.x * 256 + threadIdx.x;
  float4 v = ((const float4*)src)[i];
  ushort4 o;
  o.x = f2bf(v.x); o.y = f2bf(v.y); o.z = f2bf(v.z); o.w = f2bf(v.w);
  ((ushort4*)dst)[i] = o;
}

// ---------- GEMM core body ----------
// Computes acc for C[m0:m0+128, n0:n0+128] = A*B^T. LDS XOR-swizzled, dbuf.
__device__ __forceinline__ void gemm_core(const unsigned short* __restrict__ A,
                                          const unsigned short* __restrict__ B,
                                          int m0, int n0, int tid,
                                          unsigned short (*As)[64 * 64],
                                          unsigned short (*Bs)[64 * 64],
                                          f32x4 acc[4][4]) {
  constexpr int K = 1024;
  const int lane = tid & 63;
  const int wr = (tid >> 6) >> 1, wc = (tid >> 6) & 1;
  const int lrow = lane & 15, lg = lane >> 4;

  const int sr = tid >> 3, sseg = tid & 7;
  const int slog = sseg ^ (sr & 7);
  const int mA = sr + 64 * (slog >> 2);
  const int kof = (slog & 3) * 8;
  const unsigned short* ga  = A + (size_t)(m0 + mA) * K + kof;
  const unsigned short* ga2 = A + (size_t)(m0 + mA + 32) * K + kof;
  const unsigned short* gb  = B + (size_t)(n0 + mA) * K + kof;
  const unsigned short* gb2 = B + (size_t)(n0 + mA + 32) * K + kof;

  gload16(ga,  (char*)As[0] + tid * 16);
  gload16(ga2, (char*)As[0] + tid * 16 + 4096);
  gload16(gb,  (char*)Bs[0] + tid * 16);
  gload16(gb2, (char*)Bs[0] + tid * 16 + 4096);
  __syncthreads();

  int cur = 0;
  for (int k0 = 0; k0 < K; k0 += 32) {
    if (k0 + 32 < K) {
      const int nxt = cur ^ 1;
      gload16(ga  + k0 + 32, (char*)As[nxt] + tid * 16);
      gload16(ga2 + k0 + 32, (char*)As[nxt] + tid * 16 + 4096);
      gload16(gb  + k0 + 32, (char*)Bs[nxt] + tid * 16);
      gload16(gb2 + k0 + 32, (char*)Bs[nxt] + tid * 16 + 4096);
    }

    short8 af[4], bfr[4];
#pragma unroll
    for (int mt = 0; mt < 4; ++mt)
      af[mt] = lds8s(As[cur], mt * 16 + lrow, (wr * 4 + lg) * 16);
#pragma unroll
    for (int nt = 0; nt < 4; ++nt)
      bfr[nt] = lds8s(Bs[cur], nt * 16 + lrow, (wc * 4 + lg) * 16);
#pragma unroll
    for (int mt = 0; mt < 4; ++mt)
#pragma unroll
      for (int nt = 0; nt < 4; ++nt)
        acc[mt][nt] = __builtin_amdgcn_mfma_f32_16x16x32_bf16(af[mt], bfr[nt],
                                                              acc[mt][nt], 0, 0, 0);
    __syncthreads();
    cur ^= 1;
  }
}

// ---------- merged QKV projection: blockIdx.z selects {q,k,v} ----------
__global__ __launch_bounds__(256) void gemm_qkv(const unsigned short* __restrict__ xq,
                                                const unsigned short* __restrict__ xk,
                                                const unsigned short* __restrict__ xv,
                                                const unsigned short* __restrict__ wq,
                                                const unsigned short* __restrict__ wk,
                                                const unsigned short* __restrict__ wv,
                                                const float* __restrict__ bq,
                                                const float* __restrict__ bk,
                                                const float* __restrict__ bv,
                                                unsigned short* __restrict__ qhb,
                                                unsigned short* __restrict__ khb,
                                                unsigned short* __restrict__ vthb) {
  __shared__ __align__(16) unsigned short As[2][64 * 64];
  __shared__ __align__(16) unsigned short Bs[2][64 * 64];
  const int tid = threadIdx.x;
  const int lane = tid & 63, w = tid >> 6;
  const int wr = w >> 1, wc = w & 1;
  const int lrow = lane & 15, lg = lane >> 4;
  const int m0 = blockIdx.y * 128, n0 = blockIdx.x * 128;

  const unsigned short* A;
  const unsigned short* B;
  const float* bias;
  unsigned short* outb;
  int vmode;
  switch (blockIdx.z) {   // uniform
    case 0:  A = xq; B = wq; bias = bq; outb = qhb;  vmode = 0; break;
    case 1:  A = xk; B = wk; bias = bk; outb = khb;  vmode = 0; break;
    default: A = xv; B = wv; bias = bv; outb = vthb; vmode = 1; break;
  }

  f32x4 acc[4][4] = {};
  gemm_core(A, B, m0, n0, tid, As, Bs, acc);

#pragma unroll
  for (int mt = 0; mt < 4; ++mt) {
#pragma unroll
    for (int nt = 0; nt < 4; ++nt) {
      const int col = n0 + wc * 64 + nt * 16 + lrow;
      const float bv = bias[col];
#pragma unroll
      for (int r = 0; r < 4; ++r) {
        const int row = m0 + wr * 64 + mt * 16 + lg * 4 + r;  // token-row = l*4+n
        const float v = acc[mt][nt][r] + bv;
        const int l = row >> 2, n = row & 3, h = col >> 6, d = col & 63;
        if (vmode == 0) {
          outb[(((size_t)(n * HH + h)) * LL + l) * DD + d] = f2bf(v);
        } else {
          outb[(((size_t)(n * HH + h)) * DD + d) * LL + l] = f2bf(v);
        }
      }
    }
  }
}

// ---------- flash attention: QBLK=128, XCD-swizzled grid (R16/R18 form) ----------
__global__ __launch_bounds__(256) void flash_attn(const unsigned short* __restrict__ qh,
                                                  const unsigned short* __restrict__ kh,
                                                  const unsigned short* __restrict__ vth,
                                                  unsigned short* __restrict__ oh,
                                                  float* __restrict__ cT) {
  __shared__ __align__(16) unsigned short Ks[64 * 64];    // 8KB
  __shared__ __align__(16) unsigned short Vts[64 * 64];   // 8KB
  __shared__ __align__(16) unsigned short QPs[128 * 64];  // 16KB: Q tile then P tile
  const int tid = threadIdx.x, lane = tid & 63, w = tid >> 6;
  const int lrow = lane & 15, lg = lane >> 4;
  const int flat = blockIdx.x + (blockIdx.y << 4);
  const int nh = ((flat >> 7) << 3) | (flat & 7);
  const int l0 = ((flat >> 3) & 15) * 128;

  const unsigned short* qbase = qh + ((size_t)nh * LL + l0) * DD;
  const unsigned short* kbase = kh + (size_t)nh * LL * DD;
  const unsigned short* vbase = vth + (size_t)nh * DD * LL;

  const int sr = tid >> 3;
  const int cs = ((tid & 7) ^ (sr & 7)) * 8;

#pragma unroll
  for (int c = 0; c < 4; ++c)
    gload16(qbase + (size_t)(c * 32 + sr) * DD + cs, (char*)QPs + c * 4096 + tid * 16);
  gload16(kbase + (size_t)sr * DD + cs,        (char*)Ks + tid * 16);
  gload16(kbase + (size_t)(sr + 32) * DD + cs, (char*)Ks + tid * 16 + 4096);
  gload16(vbase + (size_t)sr * LL + cs,        (char*)Vts + tid * 16);
  gload16(vbase + (size_t)(sr + 32) * LL + cs, (char*)Vts + tid * 16 + 4096);
  __syncthreads();

  short8 qa[2][2];
#pragma unroll
  for (int qs = 0; qs < 2; ++qs) {
    qa[qs][0] = lds8s(QPs, w * 32 + qs * 16 + lrow, lg * 16);
    qa[qs][1] = lds8s(QPs, w * 32 + qs * 16 + lrow, 64 + lg * 16);
  }

  const short onev = (short)0x3F80;
  const short8 ones = {onev, onev, onev, onev, onev, onev, onev, onev};
  const f32x4 fz = {};

  f32x4 acco[2][4] = {};
  f32x4 accz[2] = {};

  const unsigned short* kpre = kbase + (size_t)(64 + sr) * DD + cs;
  const unsigned short* vpre = vbase + (size_t)sr * LL + 64 + cs;

  const int prow0 = w * 32 + lrow;

#pragma unroll 1
  for (int t = 0; t < 32; ++t) {
    const bool pf = (t < 31);

    f32x4 sc0[4];
    __builtin_amdgcn_s_setprio(1);
#pragma unroll
    for (int ct = 0; ct < 4; ++ct) {
      short8 b0 = lds8s(Ks, ct * 16 + lrow, lg * 16);
      short8 b1 = lds8s(Ks, ct * 16 + lrow, 64 + lg * 16);
      sc0[ct] = __builtin_amdgcn_mfma_f32_16x16x32_bf16(
          b1, qa[0][1],
          __builtin_amdgcn_mfma_f32_16x16x32_bf16(b0, qa[0][0], fz, 0, 0, 0),
          0, 0, 0);
    }
    __builtin_amdgcn_s_setprio(0);

#pragma unroll
    for (int ct = 0; ct < 4; ++ct) {
      float e0 = __builtin_exp2f(__builtin_fmaf(sc0[ct][0], SC2, -MFIX));
      float e1 = __builtin_exp2f(__builtin_fmaf(sc0[ct][1], SC2, -MFIX));
      float e2 = __builtin_exp2f(__builtin_fmaf(sc0[ct][2], SC2, -MFIX));
      float e3 = __builtin_exp2f(__builtin_fmaf(sc0[ct][3], SC2, -MFIX));
      unsigned int p0, p1;
      asm("v_cvt_pk_bf16_f32 %0, %1, %2" : "=v"(p0) : "v"(e0), "v"(e1));
      asm("v_cvt_pk_bf16_f32 %0, %1, %2" : "=v"(p1) : "v"(e2), "v"(e3));
      const int a = (prow0 << 7) + ((((ct * 2 + (lg >> 1)) ^ (prow0 & 7)) << 4) | ((lg & 1) << 3));
      uint2 u; u.x = p0; u.y = p1;
      *(uint2*)((char*)QPs + a) = u;
    }

    f32x4 sc1[4];
    __builtin_amdgcn_s_setprio(1);
#pragma unroll
    for (int ct = 0; ct < 4; ++ct) {
      short8 b0 = lds8s(Ks, ct * 16 + lrow, lg * 16);
      short8 b1 = lds8s(Ks, ct * 16 + lrow, 64 + lg * 16);
      sc1[ct] = __builtin_amdgcn_mfma_f32_16x16x32_bf16(
          b1, qa[1][1],
          __builtin_amdgcn_mfma_f32_16x16x32_bf16(b0, qa[1][0], fz, 0, 0, 0),
          0, 0, 0);
    }
    __builtin_amdgcn_s_setprio(0);

    __syncthreads();   // barA
    if (pf) {
      gload16(kpre,                   (char*)Ks + tid * 16);
      gload16(kpre + (size_t)32 * DD, (char*)Ks + tid * 16 + 4096);
      kpre += (size_t)64 * DD;
    }

    const int prow1 = prow0 + 16;
#pragma unroll
    for (int ct = 0; ct < 4; ++ct) {
      float e0 = __builtin_exp2f(__builtin_fmaf(sc1[ct][0], SC2, -MFIX));
      float e1 = __builtin_exp2f(__builtin_fmaf(sc1[ct][1], SC2, -MFIX));
      float e2 = __builtin_exp2f(__builtin_fmaf(sc1[ct][2], SC2, -MFIX));
      float e3 = __builtin_exp2f(__builtin_fmaf(sc1[ct][3], SC2, -MFIX));
      unsigned int p0, p1;
      asm("v_cvt_pk_bf16_f32 %0, %1, %2" : "=v"(p0) : "v"(e0), "v"(e1));
      asm("v_cvt_pk_bf16_f32 %0, %1, %2" : "=v"(p1) : "v"(e2), "v"(e3));
      const int a = (prow1 << 7) + ((((ct * 2 + (lg >> 1)) ^ (prow1 & 7)) << 4) | ((lg & 1) << 3));
      uint2 u; u.x = p0; u.y = p1;
      *(uint2*)((char*)QPs + a) = u;
    }

    short8 pa00 = lds8s(QPs, prow0, lg * 16);
    short8 pa01 = lds8s(QPs, prow0, 64 + lg * 16);
    short8 pa10 = lds8s(QPs, prow1, lg * 16);
    short8 pa11 = lds8s(QPs, prow1, 64 + lg * 16);
    __builtin_amdgcn_s_setprio(1);
#pragma unroll
    for (int dt = 0; dt < 4; ++dt) {
      short8 vb0 = lds8s(Vts, dt * 16 + lrow, lg * 16);
      short8 vb1 = lds8s(Vts, dt * 16 + lrow, 64 + lg * 16);
      acco[0][dt] = __builtin_amdgcn_mfma_f32_16x16x32_bf16(vb0, pa00, acco[0][dt], 0, 0, 0);
      acco[0][dt] = __builtin_amdgcn_mfma_f32_16x16x32_bf16(vb1, pa01, acco[0][dt], 0, 0, 0);
      acco[1][dt] = __builtin_amdgcn_mfma_f32_16x16x32_bf16(vb0, pa10, acco[1][dt], 0, 0, 0);
      acco[1][dt] = __builtin_amdgcn_mfma_f32_16x16x32_bf16(vb1, pa11, acco[1][dt], 0, 0, 0);
    }
    accz[0] = __builtin_amdgcn_mfma_f32_16x16x32_bf16(ones, pa00, accz[0], 0, 0, 0);
    accz[0] = __builtin_amdgcn_mfma_f32_16x16x32_bf16(ones, pa01, accz[0], 0, 0, 0);
    accz[1] = __builtin_amdgcn_mfma_f32_16x16x32_bf16(ones, pa10, accz[1], 0, 0, 0);
    accz[1] = __builtin_amdgcn_mfma_f32_16x16x32_bf16(ones, pa11, accz[1], 0, 0, 0);
    __builtin_amdgcn_s_setprio(0);

    __syncthreads();   // barB
    if (pf) {
      gload16(vpre,                   (char*)Vts + tid * 16);
      gload16(vpre + (size_t)32 * LL, (char*)Vts + tid * 16 + 4096);
      vpre += 64;
    }
  }

  const int n = nh >> 4, h = nh & 15;
#pragma unroll
  for (int qs = 0; qs < 2; ++qs) {
    const int lt = l0 + w * 32 + qs * 16 + lrow;
    const float zrow = accz[qs][0];
    const float rz = 1.0f / zrow;
#pragma unroll
    for (int dt = 0; dt < 4; ++dt) {
      ushort4 o;
      o.x = f2bf(acco[qs][dt][0] * rz);
      o.y = f2bf(acco[qs][dt][1] * rz);
      o.z = f2bf(acco[qs][dt][2] * rz);
      o.w = f2bf(acco[qs][dt][3] * rz);
      *(ushort4*)&oh[((size_t)lt * NB + n) * EE + h * 64 + dt * 16 + lg * 4] = o;
    }
    if (lg == 0) {
      cT[((size_t)n * LL + lt) * HH + h] = -(MFIX + __builtin_log2f(zrow));
    }
  }
}

// ---------- fused tail: z=0 -> O-projection GEMM, z=1..4 -> weights_mean ----------
// The two roles are INDEPENDENT (both consume only flash outputs; disjoint
// writes out0/out1), so one dispatch lets gemm_o (512 blocks, issued first)
// overlap with weights_mean's 4096 blocks instead of serializing.
__global__ __launch_bounds__(256) void tail_fused(const unsigned short* __restrict__ oh,
                                                  const unsigned short* __restrict__ wob,
                                                  const float* __restrict__ bo,
                                                  float* __restrict__ out0,
                                                  const unsigned short* __restrict__ qh,
                                                  const unsigned short* __restrict__ kh,
                                                  const float* __restrict__ cT,
                                                  float* __restrict__ out1) {
  __shared__ __align__(16) unsigned short smem[2][2][64 * 64];  // 32KB
  const int tid = threadIdx.x, lane = tid & 63, w = tid >> 6;
  const int lrow = lane & 15, lg = lane >> 4;

  if (blockIdx.z == 0) {
    // ---- O-projection role ----
    const int flat = blockIdx.y * 32 + blockIdx.x;
    if (flat >= 512) return;
    const int m0 = (flat >> 3) * 128, n0 = (flat & 7) * 128;
    const int wr = w >> 1, wc = w & 1;

    f32x4 acc[4][4] = {};
    gemm_core(oh, wob, m0, n0, tid, smem[0], smem[1], acc);

#pragma unroll
    for (int mt = 0; mt < 4; ++mt) {
#pragma unroll
      for (int nt = 0; nt < 4; ++nt) {
        const int col = n0 + wc * 64 + nt * 16 + lrow;
        const float bv = bo[col];
#pragma unroll
        for (int r = 0; r < 4; ++r) {
          const int row = m0 + wr * 64 + mt * 16 + lg * 4 + r;
          out0[(size_t)row * EE + col] = acc[mt][nt][r] + bv;
        }
      }
    }
    return;
  }

  // ---- weights_mean role (R14 proven structure) ----
  unsigned short* Qs = smem[0][0];
  unsigned short* Ks = smem[0][1];
  const int n = blockIdx.z - 1;
  const int l0 = blockIdx.y * 64, s0 = blockIdx.x * 64;

  const int sr = tid >> 3;
  const int cs = ((tid & 7) ^ (sr & 7)) * 8;
  const f32x4 fz = {};

  float accw[4][4] = {};
  for (int h = 0; h < HH; ++h) {
    const int nh = n * HH + h;
    __syncthreads();
    const unsigned short* qbase = qh + ((size_t)nh * LL + l0) * DD;
    const unsigned short* kbase = kh + ((size_t)nh * LL + s0) * DD;
    gload16(qbase + (size_t)sr * DD + cs,        (char*)Qs + tid * 16);
    gload16(qbase + (size_t)(sr + 32) * DD + cs, (char*)Qs + tid * 16 + 4096);
    gload16(kbase + (size_t)sr * DD + cs,        (char*)Ks + tid * 16);
    gload16(kbase + (size_t)(sr + 32) * DD + cs, (char*)Ks + tid * 16 + 4096);
    __syncthreads();

    short8 qa0 = lds8s(Qs, w * 16 + lrow, lg * 16);
    short8 qa1 = lds8s(Qs, w * 16 + lrow, 64 + lg * 16);
    f32x4 sc[4];
    __builtin_amdgcn_s_setprio(1);
#pragma unroll
    for (int ct = 0; ct < 4; ++ct) {
      short8 b0 = lds8s(Ks, ct * 16 + lrow, lg * 16);
      short8 b1 = lds8s(Ks, ct * 16 + lrow, 64 + lg * 16);
      sc[ct] = __builtin_amdgcn_mfma_f32_16x16x32_bf16(
          qa1, b1,
          __builtin_amdgcn_mfma_f32_16x16x32_bf16(qa0, b0, fz, 0, 0, 0),
          0, 0, 0);
    }
    __builtin_amdgcn_s_setprio(0);
#pragma unroll
    for (int r = 0; r < 4; ++r) {
      const int lt = l0 + w * 16 + lg * 4 + r;
      const float c = cT[((size_t)n * LL + lt) * HH + h];
#pragma unroll
      for (int ct = 0; ct < 4; ++ct)
        accw[ct][r] += __builtin_exp2f(__builtin_fmaf(sc[ct][r], SC2, c));
    }
  }
#pragma unroll
  for (int ct = 0; ct < 4; ++ct)
#pragma unroll
    for (int r = 0; r < 4; ++r) {
      const int lt = l0 + w * 16 + lg * 4 + r;
      const int s = s0 + ct * 16 + lrow;
      out1[((size_t)n * LL + lt) * LL + s] = accw[ct][r] * 0.0625f;
    }
}

// ---------- launch ----------
extern "C" void kernel_launch(void* const* d_in, const int* in_sizes, int n_in,
                              void* d_out, int out_size, void* d_ws, size_t ws_size,
                              hipStream_t stream) {
  const float* query = (const float*)d_in[0];
  const float* key   = (const float*)d_in[1];
  const float* value = (const float*)d_in[2];
  const float* Wq = (const float*)d_in[3];
  const float* bq = (const float*)d_in[4];
  const float* Wk = (const float*)d_in[5];
  const float* bk = (const float*)d_in[6];
  const float* Wv = (const float*)d_in[7];
  const float* bv = (const float*)d_in[8];
  const float* Wo = (const float*)d_in[9];
  const float* bo = (const float*)d_in[10];

  float* out0 = (float*)d_out;                       // [2048,4,1024]
  float* out1 = out0 + (size_t)LL * NB * EE;         // [4,2048,2048]

  char* ws = (char*)d_ws;
  unsigned short* xq   = (unsigned short*)(ws + 0);          // 16 MB; later oh
  unsigned short* wqb  = (unsigned short*)(ws + 16777216);   // 2 MB each
  unsigned short* wkb  = (unsigned short*)(ws + 18874368);
  unsigned short* wvb  = (unsigned short*)(ws + 20971520);
  unsigned short* wob  = (unsigned short*)(ws + 23068672);
  unsigned short* qhb  = (unsigned short*)(ws + 25165824);   // 16 MB
  unsigned short* khb  = (unsigned short*)(ws + 41943040);   // 16 MB
  unsigned short* vthb = (unsigned short*)(ws + 58720256);   // 16 MB
  float* cT   = (float*)(ws + 75497472);                     // 512 KB [n][l][h]

  // key/value bf16 inputs borrow out1 (rewritten by tail_fused at the end)
  unsigned short* xk = (unsigned short*)out1;                           // 16 MB
  unsigned short* xv = (unsigned short*)((char*)out1 + 16777216);       // 16 MB

  const int nTok = MROWS * EE;    // 8,388,608
  const int nW   = EE * EE;       // 1,048,576

  conv_w4<<<dim3(nW / 1024, 4), 256, 0, stream>>>(Wq, Wk, Wv, Wo, wqb, wkb, wvb, wob);
  conv_tok3<<<dim3(nTok / 1024, 3), 256, 0, stream>>>(query, key, value, xq, xk, xv);

  gemm_qkv<<<dim3(EE / 128, MROWS / 128, 3), 256, 0, stream>>>(
      xq, xk, xv, wqb, wkb, wvb, bq, bk, bv, qhb, khb, vthb);

  flash_attn<<<dim3(LL / 128, NB * HH), 256, 0, stream>>>(qhb, khb, vthb, xq, cT);

  // fused tail: gemm_o (z=0) + weights_mean (z=1..4) in one dispatch
  tail_fused<<<dim3(32, 32, 5), 256, 0, stream>>>(xq, wob, bo, out0,
                                                  qhb, khb, cT, out1);
}

// Round 20
// 364.355 us; speedup vs baseline: 1.0518x; 1.0518x over previous
//
#include <hip/hip_runtime.h>
#include <hip/hip_bf16.h>

// ---------- types & helpers ----------
typedef __attribute__((ext_vector_type(8))) short short8;   // 8 bf16 (4 VGPRs)
typedef __attribute__((ext_vector_type(4))) float f32x4;

#define AS1 __attribute__((address_space(1)))
#define AS3 __attribute__((address_space(3)))

__device__ __forceinline__ void gload16(const void* g, void* l) {
  __builtin_amdgcn_global_load_lds((const AS1 unsigned int*)g,
                                   (AS3 unsigned int*)l, 16, 0, 0);
}

__device__ __forceinline__ unsigned short f2bf(float x) {
  unsigned u = __float_as_uint(x);
  u = (u + 0x7FFFu + ((u >> 16) & 1u)) >> 16;  // RNE
  return (unsigned short)u;
}

__device__ __forceinline__ short8 lds8(const unsigned short* p) {
  return *(const short8*)p;
}

// Swizzled 16B LDS read: logical (row, byteInRow) of a 128B-row tile.
// Swizzle: 16B-slot ^= row&7.
__device__ __forceinline__ short8 lds8s(const unsigned short* base, int row, int byteInRow) {
  const int a = (row << 7) + (byteInRow ^ ((row & 7) << 4));
  return *(const short8*)((const char*)base + a);
}

// Problem constants: L=S=2048, N=4, E=1024, H=16, D=64; rows = L*N = 8192
#define LL 2048
#define NB 4
#define EE 1024
#define HH 16
#define DD 64
#define MROWS 8192
#define SC2 0.18033688f  // 0.125 * log2(e): softmax in exp2 domain
#define MFIX 16.0f       // fixed exponent shift (max sc*SC2 ~ 6 sigma ~ 9 << 16)

// ---------- batched token conv: query/key/value in ONE dispatch ----------
__global__ __launch_bounds__(256) void conv_tok3(const float* __restrict__ s0,
                                                 const float* __restrict__ s1,
                                                 const float* __restrict__ s2,
                                                 unsigned short* __restrict__ d0,
                                                 unsigned short* __restrict__ d1,
                                                 unsigned short* __restrict__ d2) {
  const float* src;
  unsigned short* dst;
  switch (blockIdx.y) {
    case 0: src = s0; dst = d0; break;
    case 1: src = s1; dst = d1; break;
    default: src = s2; dst = d2; break;
  }
  int i = blockIdx.x * 256 + threadIdx.x;
  float4 v = ((const float4*)src)[i];
  ushort4 o;
  o.x = f2bf(v.x); o.y = f2bf(v.y); o.z = f2bf(v.z); o.w = f2bf(v.w);
  ((ushort4*)dst)[i] = o;
}

// ---------- batched 4-weight conv ----------
__global__ __launch_bounds__(256) void conv_w4(const float* __restrict__ s0,
                                               const float* __restrict__ s1,
                                               const float* __restrict__ s2,
                                               const float* __restrict__ s3,
                                               unsigned short* __restrict__ d0,
                                               unsigned short* __restrict__ d1,
                                               unsigned short* __restrict__ d2,
                                               unsigned short* __restrict__ d3) {
  const float* src;
  unsigned short* dst;
  switch (blockIdx.y) {
    case 0: src = s0; dst = d0; break;
    case 1: src = s1; dst = d1; break;
    case 2: src = s2; dst = d2; break;
    default: src = s3; dst = d3; break;
  }
  int i = blockIdx.x * 256 + threadIdx.x;
  float4 v = ((const float4*)src)[i];
  ushort4 o;
  o.x = f2bf(v.x); o.y = f2bf(v.y); o.z = f2bf(v.z); o.w = f2bf(v.w);
  ((ushort4*)dst)[i] = o;
}

// ---------- GEMM core body (shared by qkv-merged and o-projection) ----------
// Computes acc for C[m0:m0+128, n0:n0+128] = A*B^T. LDS XOR-swizzled, dbuf.
__device__ __forceinline__ void gemm_core(const unsigned short* __restrict__ A,
                                          const unsigned short* __restrict__ B,
                                          int m0, int n0, int tid,
                                          unsigned short (*As)[64 * 64],
                                          unsigned short (*Bs)[64 * 64],
                                          f32x4 acc[4][4]) {
  constexpr int K = 1024;
  const int lane = tid & 63;
  const int wr = (tid >> 6) >> 1, wc = (tid >> 6) & 1;
  const int lrow = lane & 15, lg = lane >> 4;

  const int sr = tid >> 3, sseg = tid & 7;
  const int slog = sseg ^ (sr & 7);
  const int mA = sr + 64 * (slog >> 2);
  const int kof = (slog & 3) * 8;
  const unsigned short* ga  = A + (size_t)(m0 + mA) * K + kof;
  const unsigned short* ga2 = A + (size_t)(m0 + mA + 32) * K + kof;
  const unsigned short* gb  = B + (size_t)(n0 + mA) * K + kof;
  const unsigned short* gb2 = B + (size_t)(n0 + mA + 32) * K + kof;

  gload16(ga,  (char*)As[0] + tid * 16);
  gload16(ga2, (char*)As[0] + tid * 16 + 4096);
  gload16(gb,  (char*)Bs[0] + tid * 16);
  gload16(gb2, (char*)Bs[0] + tid * 16 + 4096);
  __syncthreads();

  int cur = 0;
  for (int k0 = 0; k0 < K; k0 += 32) {
    if (k0 + 32 < K) {
      const int nxt = cur ^ 1;
      gload16(ga  + k0 + 32, (char*)As[nxt] + tid * 16);
      gload16(ga2 + k0 + 32, (char*)As[nxt] + tid * 16 + 4096);
      gload16(gb  + k0 + 32, (char*)Bs[nxt] + tid * 16);
      gload16(gb2 + k0 + 32, (char*)Bs[nxt] + tid * 16 + 4096);
    }

    short8 af[4], bfr[4];
#pragma unroll
    for (int mt = 0; mt < 4; ++mt)
      af[mt] = lds8s(As[cur], mt * 16 + lrow, (wr * 4 + lg) * 16);
#pragma unroll
    for (int nt = 0; nt < 4; ++nt)
      bfr[nt] = lds8s(Bs[cur], nt * 16 + lrow, (wc * 4 + lg) * 16);
#pragma unroll
    for (int mt = 0; mt < 4; ++mt)
#pragma unroll
      for (int nt = 0; nt < 4; ++nt)
        acc[mt][nt] = __builtin_amdgcn_mfma_f32_16x16x32_bf16(af[mt], bfr[nt],
                                                              acc[mt][nt], 0, 0, 0);
    __syncthreads();
    cur ^= 1;
  }
}

// ---------- merged QKV projection: blockIdx.z selects {q,k,v} ----------
// z=0: query->qhb [n,h,l,d]; z=1: key->khb [n,h,l,d]; z=2: value->vthb [n,h,d,s]
__global__ __launch_bounds__(256) void gemm_qkv(const unsigned short* __restrict__ xq,
                                                const unsigned short* __restrict__ xk,
                                                const unsigned short* __restrict__ xv,
                                                const unsigned short* __restrict__ wq,
                                                const unsigned short* __restrict__ wk,
                                                const unsigned short* __restrict__ wv,
                                                const float* __restrict__ bq,
                                                const float* __restrict__ bk,
                                                const float* __restrict__ bv,
                                                unsigned short* __restrict__ qhb,
                                                unsigned short* __restrict__ khb,
                                                unsigned short* __restrict__ vthb) {
  __shared__ __align__(16) unsigned short As[2][64 * 64];
  __shared__ __align__(16) unsigned short Bs[2][64 * 64];
  const int tid = threadIdx.x;
  const int lane = tid & 63, w = tid >> 6;
  const int wr = w >> 1, wc = w & 1;
  const int lrow = lane & 15, lg = lane >> 4;
  const int m0 = blockIdx.y * 128, n0 = blockIdx.x * 128;

  const unsigned short* A;
  const unsigned short* B;
  const float* bias;
  unsigned short* outb;
  int vmode;
  switch (blockIdx.z) {   // uniform
    case 0:  A = xq; B = wq; bias = bq; outb = qhb;  vmode = 0; break;
    case 1:  A = xk; B = wk; bias = bk; outb = khb;  vmode = 0; break;
    default: A = xv; B = wv; bias = bv; outb = vthb; vmode = 1; break;
  }

  f32x4 acc[4][4] = {};
  gemm_core(A, B, m0, n0, tid, As, Bs, acc);

#pragma unroll
  for (int mt = 0; mt < 4; ++mt) {
#pragma unroll
    for (int nt = 0; nt < 4; ++nt) {
      const int col = n0 + wc * 64 + nt * 16 + lrow;
      const float bv = bias[col];
#pragma unroll
      for (int r = 0; r < 4; ++r) {
        const int row = m0 + wr * 64 + mt * 16 + lg * 4 + r;  // token-row = l*4+n
        const float v = acc[mt][nt][r] + bv;
        const int l = row >> 2, n = row & 3, h = col >> 6, d = col & 63;
        if (vmode == 0) {
          outb[(((size_t)(n * HH + h)) * LL + l) * DD + d] = f2bf(v);
        } else {
          outb[(((size_t)(n * HH + h)) * DD + d) * LL + l] = f2bf(v);
        }
      }
    }
  }
}

// ---------- O-projection GEMM (bf16 A, fp32 out) ----------
__global__ __launch_bounds__(256) void gemm_o(const unsigned short* __restrict__ A,
                                              const unsigned short* __restrict__ B,
                                              const float* __restrict__ bias,
                                              float* __restrict__ outf) {
  __shared__ __align__(16) unsigned short As[2][64 * 64];
  __shared__ __align__(16) unsigned short Bs[2][64 * 64];
  const int tid = threadIdx.x;
  const int lane = tid & 63, w = tid >> 6;
  const int wr = w >> 1, wc = w & 1;
  const int lrow = lane & 15, lg = lane >> 4;
  const int m0 = blockIdx.y * 128, n0 = blockIdx.x * 128;

  f32x4 acc[4][4] = {};
  gemm_core(A, B, m0, n0, tid, As, Bs, acc);

#pragma unroll
  for (int mt = 0; mt < 4; ++mt) {
#pragma unroll
    for (int nt = 0; nt < 4; ++nt) {
      const int col = n0 + wc * 64 + nt * 16 + lrow;
      const float bv = bias[col];
#pragma unroll
      for (int r = 0; r < 4; ++r) {
        const int row = m0 + wr * 64 + mt * 16 + lg * 4 + r;
        outf[(size_t)row * EE + col] = acc[mt][nt][r] + bv;
      }
    }
  }
}

// ---------- flash attention: QBLK=128, XCD-swizzled grid (R16/R18 form) ----------
__global__ __launch_bounds__(256) void flash_attn(const unsigned short* __restrict__ qh,
                                                  const unsigned short* __restrict__ kh,
                                                  const unsigned short* __restrict__ vth,
                                                  unsigned short* __restrict__ oh,
                                                  float* __restrict__ cT) {
  __shared__ __align__(16) unsigned short Ks[64 * 64];    // 8KB
  __shared__ __align__(16) unsigned short Vts[64 * 64];   // 8KB
  __shared__ __align__(16) unsigned short QPs[128 * 64];  // 16KB: Q tile then P tile
  const int tid = threadIdx.x, lane = tid & 63, w = tid >> 6;
  const int lrow = lane & 15, lg = lane >> 4;
  const int flat = blockIdx.x + (blockIdx.y << 4);
  const int nh = ((flat >> 7) << 3) | (flat & 7);
  const int l0 = ((flat >> 3) & 15) * 128;

  const unsigned short* qbase = qh + ((size_t)nh * LL + l0) * DD;
  const unsigned short* kbase = kh + (size_t)nh * LL * DD;
  const unsigned short* vbase = vth + (size_t)nh * DD * LL;

  const int sr = tid >> 3;
  const int cs = ((tid & 7) ^ (sr & 7)) * 8;

#pragma unroll
  for (int c = 0; c < 4; ++c)
    gload16(qbase + (size_t)(c * 32 + sr) * DD + cs, (char*)QPs + c * 4096 + tid * 16);
  gload16(kbase + (size_t)sr * DD + cs,        (char*)Ks + tid * 16);
  gload16(kbase + (size_t)(sr + 32) * DD + cs, (char*)Ks + tid * 16 + 4096);
  gload16(vbase + (size_t)sr * LL + cs,        (char*)Vts + tid * 16);
  gload16(vbase + (size_t)(sr + 32) * LL + cs, (char*)Vts + tid * 16 + 4096);
  __syncthreads();

  short8 qa[2][2];
#pragma unroll
  for (int qs = 0; qs < 2; ++qs) {
    qa[qs][0] = lds8s(QPs, w * 32 + qs * 16 + lrow, lg * 16);
    qa[qs][1] = lds8s(QPs, w * 32 + qs * 16 + lrow, 64 + lg * 16);
  }

  const short onev = (short)0x3F80;
  const short8 ones = {onev, onev, onev, onev, onev, onev, onev, onev};
  const f32x4 fz = {};

  f32x4 acco[2][4] = {};
  f32x4 accz[2] = {};

  const unsigned short* kpre = kbase + (size_t)(64 + sr) * DD + cs;
  const unsigned short* vpre = vbase + (size_t)sr * LL + 64 + cs;

  const int prow0 = w * 32 + lrow;

#pragma unroll 1
  for (int t = 0; t < 32; ++t) {
    const bool pf = (t < 31);

    f32x4 sc0[4];
    __builtin_amdgcn_s_setprio(1);
#pragma unroll
    for (int ct = 0; ct < 4; ++ct) {
      short8 b0 = lds8s(Ks, ct * 16 + lrow, lg * 16);
      short8 b1 = lds8s(Ks, ct * 16 + lrow, 64 + lg * 16);
      sc0[ct] = __builtin_amdgcn_mfma_f32_16x16x32_bf16(
          b1, qa[0][1],
          __builtin_amdgcn_mfma_f32_16x16x32_bf16(b0, qa[0][0], fz, 0, 0, 0),
          0, 0, 0);
    }
    __builtin_amdgcn_s_setprio(0);

#pragma unroll
    for (int ct = 0; ct < 4; ++ct) {
      float e0 = __builtin_exp2f(__builtin_fmaf(sc0[ct][0], SC2, -MFIX));
      float e1 = __builtin_exp2f(__builtin_fmaf(sc0[ct][1], SC2, -MFIX));
      float e2 = __builtin_exp2f(__builtin_fmaf(sc0[ct][2], SC2, -MFIX));
      float e3 = __builtin_exp2f(__builtin_fmaf(sc0[ct][3], SC2, -MFIX));
      unsigned int p0, p1;
      asm("v_cvt_pk_bf16_f32 %0, %1, %2" : "=v"(p0) : "v"(e0), "v"(e1));
      asm("v_cvt_pk_bf16_f32 %0, %1, %2" : "=v"(p1) : "v"(e2), "v"(e3));
      const int a = (prow0 << 7) + ((((ct * 2 + (lg >> 1)) ^ (prow0 & 7)) << 4) | ((lg & 1) << 3));
      uint2 u; u.x = p0; u.y = p1;
      *(uint2*)((char*)QPs + a) = u;
    }

    f32x4 sc1[4];
    __builtin_amdgcn_s_setprio(1);
#pragma unroll
    for (int ct = 0; ct < 4; ++ct) {
      short8 b0 = lds8s(Ks, ct * 16 + lrow, lg * 16);
      short8 b1 = lds8s(Ks, ct * 16 + lrow, 64 + lg * 16);
      sc1[ct] = __builtin_amdgcn_mfma_f32_16x16x32_bf16(
          b1, qa[1][1],
          __builtin_amdgcn_mfma_f32_16x16x32_bf16(b0, qa[1][0], fz, 0, 0, 0),
          0, 0, 0);
    }
    __builtin_amdgcn_s_setprio(0);

    __syncthreads();   // barA
    if (pf) {
      gload16(kpre,                   (char*)Ks + tid * 16);
      gload16(kpre + (size_t)32 * DD, (char*)Ks + tid * 16 + 4096);
      kpre += (size_t)64 * DD;
    }

    const int prow1 = prow0 + 16;
#pragma unroll
    for (int ct = 0; ct < 4; ++ct) {
      float e0 = __builtin_exp2f(__builtin_fmaf(sc1[ct][0], SC2, -MFIX));
      float e1 = __builtin_exp2f(__builtin_fmaf(sc1[ct][1], SC2, -MFIX));
      float e2 = __builtin_exp2f(__builtin_fmaf(sc1[ct][2], SC2, -MFIX));
      float e3 = __builtin_exp2f(__builtin_fmaf(sc1[ct][3], SC2, -MFIX));
      unsigned int p0, p1;
      asm("v_cvt_pk_bf16_f32 %0, %1, %2" : "=v"(p0) : "v"(e0), "v"(e1));
      asm("v_cvt_pk_bf16_f32 %0, %1, %2" : "=v"(p1) : "v"(e2), "v"(e3));
      const int a = (prow1 << 7) + ((((ct * 2 + (lg >> 1)) ^ (prow1 & 7)) << 4) | ((lg & 1) << 3));
      uint2 u; u.x = p0; u.y = p1;
      *(uint2*)((char*)QPs + a) = u;
    }

    short8 pa00 = lds8s(QPs, prow0, lg * 16);
    short8 pa01 = lds8s(QPs, prow0, 64 + lg * 16);
    short8 pa10 = lds8s(QPs, prow1, lg * 16);
    short8 pa11 = lds8s(QPs, prow1, 64 + lg * 16);
    __builtin_amdgcn_s_setprio(1);
#pragma unroll
    for (int dt = 0; dt < 4; ++dt) {
      short8 vb0 = lds8s(Vts, dt * 16 + lrow, lg * 16);
      short8 vb1 = lds8s(Vts, dt * 16 + lrow, 64 + lg * 16);
      acco[0][dt] = __builtin_amdgcn_mfma_f32_16x16x32_bf16(vb0, pa00, acco[0][dt], 0, 0, 0);
      acco[0][dt] = __builtin_amdgcn_mfma_f32_16x16x32_bf16(vb1, pa01, acco[0][dt], 0, 0, 0);
      acco[1][dt] = __builtin_amdgcn_mfma_f32_16x16x32_bf16(vb0, pa10, acco[1][dt], 0, 0, 0);
      acco[1][dt] = __builtin_amdgcn_mfma_f32_16x16x32_bf16(vb1, pa11, acco[1][dt], 0, 0, 0);
    }
    accz[0] = __builtin_amdgcn_mfma_f32_16x16x32_bf16(ones, pa00, accz[0], 0, 0, 0);
    accz[0] = __builtin_amdgcn_mfma_f32_16x16x32_bf16(ones, pa01, accz[0], 0, 0, 0);
    accz[1] = __builtin_amdgcn_mfma_f32_16x16x32_bf16(ones, pa10, accz[1], 0, 0, 0);
    accz[1] = __builtin_amdgcn_mfma_f32_16x16x32_bf16(ones, pa11, accz[1], 0, 0, 0);
    __builtin_amdgcn_s_setprio(0);

    __syncthreads();   // barB
    if (pf) {
      gload16(vpre,                   (char*)Vts + tid * 16);
      gload16(vpre + (size_t)32 * LL, (char*)Vts + tid * 16 + 4096);
      vpre += 64;
    }
  }

  const int n = nh >> 4, h = nh & 15;
#pragma unroll
  for (int qs = 0; qs < 2; ++qs) {
    const int lt = l0 + w * 32 + qs * 16 + lrow;
    const float zrow = accz[qs][0];
    const float rz = 1.0f / zrow;
#pragma unroll
    for (int dt = 0; dt < 4; ++dt) {
      ushort4 o;
      o.x = f2bf(acco[qs][dt][0] * rz);
      o.y = f2bf(acco[qs][dt][1] * rz);
      o.z = f2bf(acco[qs][dt][2] * rz);
      o.w = f2bf(acco[qs][dt][3] * rz);
      *(ushort4*)&oh[((size_t)lt * NB + n) * EE + h * 64 + dt * 16 + lg * 4] = o;
    }
    if (lg == 0) {
      cT[((size_t)n * LL + lt) * HH + h] = -(MFIX + __builtin_log2f(zrow));
    }
  }
}

// ---------- weights mean: out1[n][l][s] = (1/16) sum_h exp2(sc*SC2 + c_h) ----------
__global__ __launch_bounds__(256) void weights_mean(const unsigned short* __restrict__ qh,
                                                    const unsigned short* __restrict__ kh,
                                                    const float* __restrict__ cT,
                                                    float* __restrict__ out1) {
  __shared__ __align__(16) unsigned short Qs[64 * 64];
  __shared__ __align__(16) unsigned short Ks[64 * 64];
  const int tid = threadIdx.x, lane = tid & 63, w = tid >> 6;
  const int lrow = lane & 15, lg = lane >> 4;
  const int n = blockIdx.z;
  const int l0 = blockIdx.y * 64, s0 = blockIdx.x * 64;

  const int sr = tid >> 3;
  const int cs = ((tid & 7) ^ (sr & 7)) * 8;
  const f32x4 fz = {};

  float accw[4][4] = {};
  for (int h = 0; h < HH; ++h) {
    const int nh = n * HH + h;
    __syncthreads();
    const unsigned short* qbase = qh + ((size_t)nh * LL + l0) * DD;
    const unsigned short* kbase = kh + ((size_t)nh * LL + s0) * DD;
    gload16(qbase + (size_t)sr * DD + cs,        (char*)Qs + tid * 16);
    gload16(qbase + (size_t)(sr + 32) * DD + cs, (char*)Qs + tid * 16 + 4096);
    gload16(kbase + (size_t)sr * DD + cs,        (char*)Ks + tid * 16);
    gload16(kbase + (size_t)(sr + 32) * DD + cs, (char*)Ks + tid * 16 + 4096);
    __syncthreads();

    short8 qa0 = lds8s(Qs, w * 16 + lrow, lg * 16);
    short8 qa1 = lds8s(Qs, w * 16 + lrow, 64 + lg * 16);
    f32x4 sc[4];
    __builtin_amdgcn_s_setprio(1);
#pragma unroll
    for (int ct = 0; ct < 4; ++ct) {
      short8 b0 = lds8s(Ks, ct * 16 + lrow, lg * 16);
      short8 b1 = lds8s(Ks, ct * 16 + lrow, 64 + lg * 16);
      sc[ct] = __builtin_amdgcn_mfma_f32_16x16x32_bf16(
          qa1, b1,
          __builtin_amdgcn_mfma_f32_16x16x32_bf16(qa0, b0, fz, 0, 0, 0),
          0, 0, 0);
    }
    __builtin_amdgcn_s_setprio(0);
#pragma unroll
    for (int r = 0; r < 4; ++r) {
      const int lt = l0 + w * 16 + lg * 4 + r;
      const float c = cT[((size_t)n * LL + lt) * HH + h];
#pragma unroll
      for (int ct = 0; ct < 4; ++ct)
        accw[ct][r] += __builtin_exp2f(__builtin_fmaf(sc[ct][r], SC2, c));
    }
  }
#pragma unroll
  for (int ct = 0; ct < 4; ++ct)
#pragma unroll
    for (int r = 0; r < 4; ++r) {
      const int lt = l0 + w * 16 + lg * 4 + r;
      const int s = s0 + ct * 16 + lrow;
      out1[((size_t)n * LL + lt) * LL + s] = accw[ct][r] * 0.0625f;
    }
}

// ---------- launch ----------
extern "C" void kernel_launch(void* const* d_in, const int* in_sizes, int n_in,
                              void* d_out, int out_size, void* d_ws, size_t ws_size,
                              hipStream_t stream) {
  const float* query = (const float*)d_in[0];
  const float* key   = (const float*)d_in[1];
  const float* value = (const float*)d_in[2];
  const float* Wq = (const float*)d_in[3];
  const float* bq = (const float*)d_in[4];
  const float* Wk = (const float*)d_in[5];
  const float* bk = (const float*)d_in[6];
  const float* Wv = (const float*)d_in[7];
  const float* bv = (const float*)d_in[8];
  const float* Wo = (const float*)d_in[9];
  const float* bo = (const float*)d_in[10];

  float* out0 = (float*)d_out;                       // [2048,4,1024]
  float* out1 = out0 + (size_t)LL * NB * EE;         // [4,2048,2048]

  char* ws = (char*)d_ws;
  unsigned short* xq   = (unsigned short*)(ws + 0);          // 16 MB; later oh
  unsigned short* wqb  = (unsigned short*)(ws + 16777216);   // 2 MB each
  unsigned short* wkb  = (unsigned short*)(ws + 18874368);
  unsigned short* wvb  = (unsigned short*)(ws + 20971520);
  unsigned short* wob  = (unsigned short*)(ws + 23068672);
  unsigned short* qhb  = (unsigned short*)(ws + 25165824);   // 16 MB
  unsigned short* khb  = (unsigned short*)(ws + 41943040);   // 16 MB
  unsigned short* vthb = (unsigned short*)(ws + 58720256);   // 16 MB
  float* cT   = (float*)(ws + 75497472);                     // 512 KB [n][l][h]

  // key/value bf16 inputs borrow out1 (weights_mean rewrites out1 at the end;
  // these are only read during the QKV gemms)
  unsigned short* xk = (unsigned short*)out1;                           // 16 MB
  unsigned short* xv = (unsigned short*)((char*)out1 + 16777216);       // 16 MB

  const int nTok = MROWS * EE;    // 8,388,608
  const int nW   = EE * EE;       // 1,048,576

  conv_w4<<<dim3(nW / 1024, 4), 256, 0, stream>>>(Wq, Wk, Wv, Wo, wqb, wkb, wvb, wob);
  conv_tok3<<<dim3(nTok / 1024, 3), 256, 0, stream>>>(query, key, value, xq, xk, xv);

  // all three projections in ONE dispatch (1536 blocks -> 6/CU)
  gemm_qkv<<<dim3(EE / 128, MROWS / 128, 3), 256, 0, stream>>>(
      xq, xk, xv, wqb, wkb, wvb, bq, bk, bv, qhb, khb, vthb);

  flash_attn<<<dim3(LL / 128, NB * HH), 256, 0, stream>>>(qhb, khb, vthb, xq, cT);

  gemm_o<<<dim3(EE / 128, MROWS / 128), 256, 0, stream>>>(xq, wob, bo, out0);

  weights_mean<<<dim3(LL / 64, LL / 64, NB), 256, 0, stream>>>(qhb, khb, cT, out1);
}